// Round 16
// baseline (208.487 us; speedup 1.0000x reference)
//
#include <hip/hip_runtime.h>
#include <math.h>

#define NPTS  16384
#define G     32              // grid cells per axis
#define NC    (G * G * G)     // 32768 cells per set
#define CW    0.25f           // cell width: domain [-4,4]
#define ICW   4.0f            // 1/CW
#define TOTP  65536           // 4 sets x 16384 points
#define TOTQ  32768           // queries per direction-sum denominator

// set id: cloud*2 + batch. query set z (0..3) -> ref set = z^2 (other cloud, same batch)

__device__ __forceinline__ int cellof(float x) {
    int c = (int)floorf((x + 4.0f) * ICW);
    return min(max(c, 0), G - 1);
}

__global__ __launch_bounds__(256) void zero_kernel(int* __restrict__ hist) {
    hist[blockIdx.x * 256 + threadIdx.x] = 0;   // 512 blocks x 256 = 131072
}

// decode point, write packed float4 (w = orig index bits), cell id, histogram
__global__ __launch_bounds__(256) void hist_kernel(const float* __restrict__ pred,
                                                   const float* __restrict__ target,
                                                   float4* __restrict__ pts,
                                                   int* __restrict__ cellids,
                                                   int* __restrict__ hist) {
    int t = blockIdx.x * 256 + threadIdx.x;      // 0..65535
    int cloud = t >> 15, w = t & 32767, b = w >> 14, i = w & 16383;
    const float* src = cloud ? target : pred;
    float x = src[(b * NPTS + i) * 3 + 0];
    float y = src[(b * NPTS + i) * 3 + 1];
    float z = src[(b * NPTS + i) * 3 + 2];
    int set = cloud * 2 + b;
    int c = (cellof(z) * G + cellof(y)) * G + cellof(x);
    int u = (set << 14) + i;
    pts[u] = make_float4(x, y, z, __int_as_float(i));
    cellids[u] = c;
    atomicAdd(&hist[(set << 15) + c], 1);
}

// per-set exclusive scan of 32768 counts -> cs (CSR starts, +1 sentinel) and next (working copy)
__global__ __launch_bounds__(1024) void scan_kernel(const int* __restrict__ hist,
                                                    int* __restrict__ cs,
                                                    int* __restrict__ next) {
    __shared__ int tsum[1024];
    const int s = blockIdx.x;            // set 0..3
    const int tid = threadIdx.x;
    int v[32]; int sum = 0;
    const int base = (s << 15) + tid * 32;
    #pragma unroll
    for (int r = 0; r < 32; ++r) { v[r] = hist[base + r]; sum += v[r]; }
    tsum[tid] = sum;
    __syncthreads();
    for (int off = 1; off < 1024; off <<= 1) {
        int x = (tid >= off) ? tsum[tid - off] : 0;
        __syncthreads();
        tsum[tid] += x;
        __syncthreads();
    }
    int run = (tid > 0) ? tsum[tid - 1] : 0;
    const int cbase = s * (NC + 1) + tid * 32;
    #pragma unroll
    for (int r = 0; r < 32; ++r) {
        cs[cbase + r] = run;
        next[base + r] = run;
        run += v[r];
    }
    if (tid == 1023) cs[s * (NC + 1) + NC] = run;   // = 16384
}

__global__ __launch_bounds__(256) void scatter_kernel(const float4* __restrict__ pts,
                                                      const int* __restrict__ cellids,
                                                      int* __restrict__ next,
                                                      float4* __restrict__ sorted) {
    int u = blockIdx.x * 256 + threadIdx.x;      // 0..65535
    int set = u >> 14;
    int c = cellids[u];
    int idx = atomicAdd(&next[(set << 15) + c], 1);
    sorted[(set << 14) + idx] = pts[u];
}

#define EVAL(j) { float4 p = sr[j];                                   \
    float dx = q.x - p.x, dy = q.y - p.y, dz = q.z - p.z;             \
    md2 = fminf(md2, fmaf(dx, dx, fmaf(dy, dy, dz * dz))); }

// exact NN via expanding Chebyshev shells over the CSR grid
__global__ __launch_bounds__(256) void nn_kernel(const float4* __restrict__ sorted,
                                                 const int* __restrict__ cs,
                                                 float* __restrict__ dout) {
    const int z = blockIdx.y;                           // query set
    const int qi = blockIdx.x * 256 + threadIdx.x;      // sorted-order query (locality)
    float4 q = sorted[(z << 14) + qi];
    const float4* __restrict__ sr = sorted + ((z ^ 2) << 14);
    const int* __restrict__ csr = cs + (z ^ 2) * (NC + 1);

    const int cx = cellof(q.x), cy = cellof(q.y), cz = cellof(q.z);
    float md2 = __builtin_inff();

    for (int k = 0; k < G; ++k) {
        const int zlo = max(cz - k, 0), zhi = min(cz + k, G - 1);
        const int ylo = max(cy - k, 0), yhi = min(cy + k, G - 1);
        const int xlo = max(cx - k, 0), xhi = min(cx + k, G - 1);
        for (int zz = zlo; zz <= zhi; ++zz) {
            const bool zf = (zz == cz - k) || (zz == cz + k);
            for (int yy = ylo; yy <= yhi; ++yy) {
                const int rowbase = (zz * G + yy) * G;
                if (zf || (yy == cy - k) || (yy == cy + k)) {
                    // full x-run: cells are contiguous in memory -> one CSR range
                    const int s0 = csr[rowbase + xlo], s1 = csr[rowbase + xhi + 1];
                    for (int j = s0; j < s1; ++j) EVAL(j)
                } else {
                    // interior row: only x = cx-k and cx+k are new (k >= 1 here)
                    const int xa = cx - k, xb = cx + k;
                    if (xa >= 0) {
                        const int s0 = csr[rowbase + xa], s1 = csr[rowbase + xa + 1];
                        for (int j = s0; j < s1; ++j) EVAL(j)
                    }
                    if (xb <= G - 1) {
                        const int s0 = csr[rowbase + xb], s1 = csr[rowbase + xb + 1];
                        for (int j = s0; j < s1; ++j) EVAL(j)
                    }
                }
            }
        }
        // exact termination: nearest possible unsearched point is >= g away.
        // faces at the domain edge contribute inf (outliers are clamped INTO edge
        // cells, which are inside the box whenever the box reaches the edge).
        float g = __builtin_inff();
        if (cx - k > 0)     g = fminf(g, q.x - ((cx - k) * CW - 4.0f));
        if (cx + k < G - 1) g = fminf(g, ((cx + k + 1) * CW - 4.0f) - q.x);
        if (cy - k > 0)     g = fminf(g, q.y - ((cy - k) * CW - 4.0f));
        if (cy + k < G - 1) g = fminf(g, ((cy + k + 1) * CW - 4.0f) - q.y);
        if (cz - k > 0)     g = fminf(g, q.z - ((cz - k) * CW - 4.0f));
        if (cz + k < G - 1) g = fminf(g, ((cz + k + 1) * CW - 4.0f) - q.z);
        if (md2 <= g * g) break;
    }

    const int oi = __float_as_int(q.w);
    dout[(z << 14) + oi] = sqrtf(md2);   // exact fp32 Euclid
}
#undef EVAL

__global__ __launch_bounds__(256) void reduceA_kernel(const float* __restrict__ dout,
                                                      float* __restrict__ partials) {
    int base = blockIdx.x * 1024;
    float s = 0.f;
    #pragma unroll
    for (int k = 0; k < 4; ++k)
        s += dout[base + k * 256 + threadIdx.x];
    #pragma unroll
    for (int off = 32; off; off >>= 1) s += __shfl_down(s, off);
    __shared__ float wsum[4];
    int lane = threadIdx.x & 63, wv = threadIdx.x >> 6;
    if (lane == 0) wsum[wv] = s;
    __syncthreads();
    if (threadIdx.x == 0) partials[blockIdx.x] = wsum[0] + wsum[1] + wsum[2] + wsum[3];
}

__global__ void reduceB_kernel(const float* __restrict__ partials, float* __restrict__ out) {
    float s = partials[threadIdx.x];
    #pragma unroll
    for (int off = 32; off; off >>= 1) s += __shfl_down(s, off);
    if (threadIdx.x == 0) out[0] = s / (float)TOTQ;
}

extern "C" void kernel_launch(void* const* d_in, const int* in_sizes, int n_in,
                              void* d_out, int out_size, void* d_ws, size_t ws_size,
                              hipStream_t stream) {
    const float* pred   = (const float*)d_in[0];
    const float* target = (const float*)d_in[1];
    char* ws = (char*)d_ws;

    // ws layout (16B-aligned blocks)
    float4* pts      = (float4*)(ws);                                  // 1 MiB
    float4* sorted   = (float4*)(ws + (size_t)1 * 1024 * 1024);        // 1 MiB
    int*    cellids  = (int*)  (ws + (size_t)2 * 1024 * 1024);         // 256 KiB
    int*    hist     = (int*)  (ws + (size_t)2 * 1024 * 1024 + 256 * 1024);  // 512 KiB
    int*    next     = (int*)  (ws + (size_t)2 * 1024 * 1024 + 768 * 1024);  // 512 KiB
    int*    cs       = (int*)  (ws + (size_t)3 * 1024 * 1024 + 256 * 1024);  // 4*(32769)*4 ~ 512 KiB
    float*  dout     = (float*)(ws + (size_t)4 * 1024 * 1024);         // 256 KiB
    float*  partials = (float*)(ws + (size_t)4 * 1024 * 1024 + 256 * 1024);
    float*  out      = (float*)d_out;

    zero_kernel<<<512, 256, 0, stream>>>(hist);
    hist_kernel<<<TOTP / 256, 256, 0, stream>>>(pred, target, pts, cellids, hist);
    scan_kernel<<<4, 1024, 0, stream>>>(hist, cs, next);
    scatter_kernel<<<TOTP / 256, 256, 0, stream>>>(pts, cellids, next, sorted);

    dim3 grid(NPTS / 256, 4);   // 64 x 4 blocks
    nn_kernel<<<grid, 256, 0, stream>>>(sorted, cs, dout);

    reduceA_kernel<<<64, 256, 0, stream>>>(dout, partials);
    reduceB_kernel<<<1, 64, 0, stream>>>(partials, out);
}